// Round 5
// baseline (460.127 us; speedup 1.0000x reference)
//
#include <hip/hip_runtime.h>

#define CDIM 128
#define KPAD 136
#define EPS 1e-5f

typedef __attribute__((ext_vector_type(8))) short short8;
typedef __attribute__((ext_vector_type(4))) float f32x4;

__device__ __forceinline__ float bf2f(unsigned short u) {
    union { unsigned int i; float f; } v; v.i = ((unsigned int)u) << 16; return v.f;
}
__device__ __forceinline__ unsigned short f2bf(float f) {
    union { float f; unsigned int i; } v; v.f = f;
    unsigned int u = v.i;
    return (unsigned short)((u + 0x7FFFu + ((u >> 16) & 1u)) >> 16);  // RNE
}

// ---------------- int degree histogram ----------------
__global__ __launch_bounds__(256) void hist_kernel(const int* __restrict__ dst,
                                                   int* __restrict__ deg, int E) {
    int e = blockIdx.x * 256 + threadIdx.x;
    if (e < E) atomicAdd(&deg[dst[e]], 1);
}

// ---------------- scan stage 1: per-1024-chunk sums of PADDED degrees ----------------
__global__ __launch_bounds__(256) void scan1_kernel(const int* __restrict__ deg,
                                                    int* __restrict__ part, int N) {
    int t = threadIdx.x;
    int base = blockIdx.x * 1024 + t * 4;
    int s = 0;
    if (base + 3 < N) {
        int4 v = *(const int4*)(deg + base);
        s = ((v.x + 7) & ~7) + ((v.y + 7) & ~7) + ((v.z + 7) & ~7) + ((v.w + 7) & ~7);
    } else {
        for (int k = 0; k < 4; ++k) { int i = base + k; if (i < N) s += (deg[i] + 7) & ~7; }
    }
    for (int off = 32; off; off >>= 1) s += __shfl_down(s, off, 64);
    __shared__ int sh[4];
    if ((t & 63) == 0) sh[t >> 6] = s;
    __syncthreads();
    if (t == 0) part[blockIdx.x] = sh[0] + sh[1] + sh[2] + sh[3];
}

// ---------------- scan stage 2: exclusive scan of <=256 partials ----------------
__global__ __launch_bounds__(256) void scan2_kernel(int* __restrict__ part, int P) {
    int t = threadIdx.x;
    __shared__ int sh[256];
    int v = (t < P) ? part[t] : 0;
    sh[t] = v;
    __syncthreads();
    for (int off = 1; off < 256; off <<= 1) {
        int u = (t >= off) ? sh[t - off] : 0;
        __syncthreads();
        sh[t] += u;
        __syncthreads();
    }
    if (t < P) part[t] = sh[t] - v;  // exclusive
}

// ---------------- scan stage 3: padded rowstart + cursor + dinv ----------------
__global__ __launch_bounds__(256) void scan3_kernel(const int* __restrict__ deg,
                                                    const int* __restrict__ part,
                                                    int* __restrict__ rowst,
                                                    int* __restrict__ cursor,
                                                    float* __restrict__ dinv, int N) {
    int t = threadIdx.x, b = blockIdx.x;
    int base = b * 1024 + t * 4;
    int d0 = 0, d1 = 0, d2 = 0, d3 = 0;
    if (base + 3 < N) {
        int4 v = *(const int4*)(deg + base);
        d0 = v.x; d1 = v.y; d2 = v.z; d3 = v.w;
    } else {
        if (base < N)     d0 = deg[base];
        if (base + 1 < N) d1 = deg[base + 1];
        if (base + 2 < N) d2 = deg[base + 2];
        if (base + 3 < N) d3 = deg[base + 3];
    }
    int p0 = (d0 + 7) & ~7, p1 = (d1 + 7) & ~7, p2 = (d2 + 7) & ~7, p3 = (d3 + 7) & ~7;
    int c0 = p0, c1 = c0 + p1, c2 = c1 + p2, c3 = c2 + p3;
    __shared__ int sh[256];
    sh[t] = c3;
    __syncthreads();
    for (int off = 1; off < 256; off <<= 1) {
        int u = (t >= off) ? sh[t - off] : 0;
        __syncthreads();
        sh[t] += u;
        __syncthreads();
    }
    int basev = part[b] + sh[t] - c3;
    int r0 = basev, r1 = basev + c0, r2 = basev + c1, r3 = basev + c2;
    if (base < N)     { rowst[base] = r0;     cursor[base] = r0;     dinv[base]   = rsqrtf((float)d0 + 1.0f); if (base == N - 1)     rowst[N] = r0 + p0; }
    if (base + 1 < N) { rowst[base + 1] = r1; cursor[base + 1] = r1; dinv[base+1] = rsqrtf((float)d1 + 1.0f); if (base + 1 == N - 1) rowst[N] = r1 + p1; }
    if (base + 2 < N) { rowst[base + 2] = r2; cursor[base + 2] = r2; dinv[base+2] = rsqrtf((float)d2 + 1.0f); if (base + 2 == N - 1) rowst[N] = r2 + p2; }
    if (base + 3 < N) { rowst[base + 3] = r3; cursor[base + 3] = r3; dinv[base+3] = rsqrtf((float)d3 + 1.0f); if (base + 3 == N - 1) rowst[N] = r3 + p3; }
}

// ---------------- scatter src + precomputed weight into padded CSR ----------------
__global__ __launch_bounds__(256) void scatter_kernel(const int* __restrict__ src,
                                                      const int* __restrict__ dst,
                                                      int* __restrict__ cursor,
                                                      const float* __restrict__ dinv,
                                                      int* __restrict__ csr,
                                                      float* __restrict__ wcsr, int E) {
    int e = blockIdx.x * 256 + threadIdx.x;
    if (e < E) {
        int d = dst[e];
        int s = src[e];
        int pos = atomicAdd(&cursor[d], 1);
        csr[pos] = s;
        wcsr[pos] = dinv[s] * dinv[d];
    }
}

// ---------------- per-feature stats over node dim (fp32 input) ----------------
__global__ __launch_bounds__(256) void stats_kernel(const float* __restrict__ v, int N,
                                                    float* __restrict__ sum,
                                                    float* __restrict__ sq) {
    __shared__ float s_sum[CDIM];
    __shared__ float s_sq[CDIM];
    int t = threadIdx.x;
    if (t < CDIM) { s_sum[t] = 0.f; s_sq[t] = 0.f; }
    __syncthreads();
    int cg = t & 31, rg = t >> 5;
    int c0 = cg * 4;
    float a0=0,a1=0,a2=0,a3=0,q0=0,q1=0,q2=0,q3=0;
    for (long row = (long)blockIdx.x * 8 + rg; row < N; row += (long)gridDim.x * 8) {
        float4 x4 = *(const float4*)(v + row * CDIM + c0);
        a0 += x4.x; q0 = fmaf(x4.x, x4.x, q0);
        a1 += x4.y; q1 = fmaf(x4.y, x4.y, q1);
        a2 += x4.z; q2 = fmaf(x4.z, x4.z, q2);
        a3 += x4.w; q3 = fmaf(x4.w, x4.w, q3);
    }
    atomicAdd(&s_sum[c0+0], a0); atomicAdd(&s_sum[c0+1], a1);
    atomicAdd(&s_sum[c0+2], a2); atomicAdd(&s_sum[c0+3], a3);
    atomicAdd(&s_sq[c0+0], q0);  atomicAdd(&s_sq[c0+1], q1);
    atomicAdd(&s_sq[c0+2], q2);  atomicAdd(&s_sq[c0+3], q3);
    __syncthreads();
    if (t < CDIM) { atomicAdd(&sum[t], s_sum[t]); atomicAdd(&sq[t], s_sq[t]); }
}

// ---------------- BN params ----------------
__global__ void prep_kernel(const float* __restrict__ sum, const float* __restrict__ sq,
                            const float* __restrict__ gamma, const float* __restrict__ beta,
                            float* __restrict__ scale, float* __restrict__ bias, float inv_n) {
    int c = threadIdx.x;
    float m = sum[c] * inv_n;
    float var = fmaf(-m, m, sq[c] * inv_n);
    float r = rsqrtf(var + EPS);
    float g = gamma[c] * r;
    scale[c] = g;
    bias[c] = fmaf(-m, g, beta[c]);
}

// ---------------- W -> bf16 transposed: Wt[n][k] = bf16(W[k][n]) ----------------
__global__ __launch_bounds__(256) void wprep_kernel(const float* __restrict__ W,
                                                    unsigned short* __restrict__ Wt) {
    int t = blockIdx.x * 256 + threadIdx.x;  // 4096 threads
    int k = t >> 5, n0 = (t & 31) * 4;
    float4 w = *(const float4*)(W + k * CDIM + n0);
    Wt[(n0 + 0) * CDIM + k] = f2bf(w.x);
    Wt[(n0 + 1) * CDIM + k] = f2bf(w.y);
    Wt[(n0 + 2) * CDIM + k] = f2bf(w.z);
    Wt[(n0 + 3) * CDIM + k] = f2bf(w.w);
}

// ---------------- MFMA GEMM: Y = bf16( (scale*X+bias) @ W ), 128-row tiles ----------
// B fragments load straight from global Wt (L1/L2-resident). A/B use the same assumed
// k-slot mapping (invariant to the HW bijection); C/D layout per m89.
template<bool BF16_IN>
__global__ __launch_bounds__(256) void gemm_mfma_kernel(const void* __restrict__ Xv,
                                                        const unsigned short* __restrict__ Wt,
                                                        const float* __restrict__ scale,
                                                        const float* __restrict__ bias,
                                                        unsigned short* __restrict__ Y, int N) {
    __shared__ unsigned short As[128 * KPAD];
    int t = threadIdx.x;
    long row0 = (long)blockIdx.x * 128;

    // stage A rows: BN-apply + bf16 cvt (128 rows x 128 cols)
    #pragma unroll
    for (int p = 0; p < 16; ++p) {
        int idx = p * 256 + t;
        int r = idx >> 5, c4 = (idx & 31) * 4;
        long row = row0 + r;
        float4 v;
        if (row < N) {
            if (BF16_IN) {
                ushort4 u = *(const ushort4*)((const unsigned short*)Xv + row * CDIM + c4);
                v = make_float4(bf2f(u.x), bf2f(u.y), bf2f(u.z), bf2f(u.w));
            } else {
                v = *(const float4*)((const float*)Xv + row * CDIM + c4);
            }
        } else {
            v = make_float4(0.f, 0.f, 0.f, 0.f);
        }
        float4 sc = *(const float4*)(scale + c4);
        float4 bi = *(const float4*)(bias + c4);
        ushort4 o;
        o.x = f2bf(fmaf(v.x, sc.x, bi.x));
        o.y = f2bf(fmaf(v.y, sc.y, bi.y));
        o.z = f2bf(fmaf(v.z, sc.z, bi.z));
        o.w = f2bf(fmaf(v.w, sc.w, bi.w));
        *(ushort4*)&As[r * KPAD + c4] = o;
    }
    __syncthreads();

    int lane = t & 63, wv = t >> 6;
    int m = lane & 15, hi = lane >> 4;

    // A fragments: 2 row-tiles x 4 k-slots
    short8 afr[2][4];
    #pragma unroll
    for (int mt = 0; mt < 2; ++mt)
        #pragma unroll
        for (int ks = 0; ks < 4; ++ks)
            afr[mt][ks] = *(const short8*)&As[(wv * 32 + mt * 16 + m) * KPAD + ks * 32 + hi * 8];
    __syncthreads();  // all A-frag reads done before repack reuses As

    f32x4 acc[2][8];
    #pragma unroll
    for (int mt = 0; mt < 2; ++mt)
        #pragma unroll
        for (int nt = 0; nt < 8; ++nt)
            acc[mt][nt] = (f32x4){0.f, 0.f, 0.f, 0.f};

    #pragma unroll
    for (int nt = 0; nt < 8; ++nt) {
        short8 b[4];
        #pragma unroll
        for (int ks = 0; ks < 4; ++ks)
            b[ks] = *(const short8*)(Wt + (nt * 16 + m) * CDIM + ks * 32 + hi * 8);
        #pragma unroll
        for (int mt = 0; mt < 2; ++mt) {
            f32x4 c = acc[mt][nt];
            c = __builtin_amdgcn_mfma_f32_16x16x32_bf16(afr[mt][0], b[0], c, 0, 0, 0);
            c = __builtin_amdgcn_mfma_f32_16x16x32_bf16(afr[mt][1], b[1], c, 0, 0, 0);
            c = __builtin_amdgcn_mfma_f32_16x16x32_bf16(afr[mt][2], b[2], c, 0, 0, 0);
            c = __builtin_amdgcn_mfma_f32_16x16x32_bf16(afr[mt][3], b[3], c, 0, 0, 0);
            acc[mt][nt] = c;
        }
    }

    // repack C to LDS for coalesced stores
    #pragma unroll
    for (int mt = 0; mt < 2; ++mt)
        #pragma unroll
        for (int nt = 0; nt < 8; ++nt)
            #pragma unroll
            for (int rg = 0; rg < 4; ++rg)
                As[(wv * 32 + mt * 16 + hi * 4 + rg) * KPAD + nt * 16 + m] = f2bf(acc[mt][nt][rg]);
    __syncthreads();
    #pragma unroll
    for (int p = 0; p < 16; ++p) {
        int idx = p * 256 + t;
        int r = idx >> 5, c4 = (idx & 31) * 4;
        long row = row0 + r;
        if (row < N) {
            ushort4 o = *(const ushort4*)&As[r * KPAD + c4];
            *(ushort4*)(Y + row * CDIM + c4) = o;
        }
    }
}

// ------ fused gather-agg + self-loop + bias + relu + BN stats (8-wide padded CSR) ------
__global__ __launch_bounds__(256) void gather_kernel(const unsigned short* __restrict__ h,
                                                     const int* __restrict__ rowst,
                                                     const int* __restrict__ csr,
                                                     const float* __restrict__ wcsr,
                                                     const float* __restrict__ dinv,
                                                     const float* __restrict__ bvec,
                                                     unsigned short* __restrict__ vout, int N,
                                                     float* __restrict__ sum,
                                                     float* __restrict__ sq) {
    __shared__ float s_sum[CDIM];
    __shared__ float s_sq[CDIM];
    int t = threadIdx.x;
    if (t < CDIM) { s_sum[t] = 0.f; s_sq[t] = 0.f; }
    __syncthreads();
    int grp = t >> 5, lane = t & 31;
    int c0 = lane * 4;
    float4 bb = *(const float4*)(bvec + c0);
    float a0=0,a1=0,a2=0,a3=0,q0=0,q1=0,q2=0,q3=0;
    int ngroups = gridDim.x * 8;
    for (int n = blockIdx.x * 8 + grp; n < N; n += ngroups) {
        int j = rowst[n], e = rowst[n + 1];  // padded: (e-j) % 8 == 0
        float dn = dinv[n];
        float d2 = dn * dn;
        ushort4 hn = *(const ushort4*)(h + (long)n * CDIM + c0);
        float x0 = bf2f(hn.x) * d2, x1 = bf2f(hn.y) * d2;
        float x2 = bf2f(hn.z) * d2, x3 = bf2f(hn.w) * d2;
        for (; j < e; j += 8) {
            int4 i0 = *(const int4*)(csr + j);
            int4 i1 = *(const int4*)(csr + j + 4);
            float4 w0 = *(const float4*)(wcsr + j);
            float4 w1 = *(const float4*)(wcsr + j + 4);
            ushort4 u0 = *(const ushort4*)(h + (long)i0.x * CDIM + c0);
            ushort4 u1 = *(const ushort4*)(h + (long)i0.y * CDIM + c0);
            ushort4 u2 = *(const ushort4*)(h + (long)i0.z * CDIM + c0);
            ushort4 u3 = *(const ushort4*)(h + (long)i0.w * CDIM + c0);
            ushort4 u4 = *(const ushort4*)(h + (long)i1.x * CDIM + c0);
            ushort4 u5 = *(const ushort4*)(h + (long)i1.y * CDIM + c0);
            ushort4 u6 = *(const ushort4*)(h + (long)i1.z * CDIM + c0);
            ushort4 u7 = *(const ushort4*)(h + (long)i1.w * CDIM + c0);
            x0 = fmaf(bf2f(u0.x), w0.x, x0); x1 = fmaf(bf2f(u0.y), w0.x, x1);
            x2 = fmaf(bf2f(u0.z), w0.x, x2); x3 = fmaf(bf2f(u0.w), w0.x, x3);
            x0 = fmaf(bf2f(u1.x), w0.y, x0); x1 = fmaf(bf2f(u1.y), w0.y, x1);
            x2 = fmaf(bf2f(u1.z), w0.y, x2); x3 = fmaf(bf2f(u1.w), w0.y, x3);
            x0 = fmaf(bf2f(u2.x), w0.z, x0); x1 = fmaf(bf2f(u2.y), w0.z, x1);
            x2 = fmaf(bf2f(u2.z), w0.z, x2); x3 = fmaf(bf2f(u2.w), w0.z, x3);
            x0 = fmaf(bf2f(u3.x), w0.w, x0); x1 = fmaf(bf2f(u3.y), w0.w, x1);
            x2 = fmaf(bf2f(u3.z), w0.w, x2); x3 = fmaf(bf2f(u3.w), w0.w, x3);
            x0 = fmaf(bf2f(u4.x), w1.x, x0); x1 = fmaf(bf2f(u4.y), w1.x, x1);
            x2 = fmaf(bf2f(u4.z), w1.x, x2); x3 = fmaf(bf2f(u4.w), w1.x, x3);
            x0 = fmaf(bf2f(u5.x), w1.y, x0); x1 = fmaf(bf2f(u5.y), w1.y, x1);
            x2 = fmaf(bf2f(u5.z), w1.y, x2); x3 = fmaf(bf2f(u5.w), w1.y, x3);
            x0 = fmaf(bf2f(u6.x), w1.z, x0); x1 = fmaf(bf2f(u6.y), w1.z, x1);
            x2 = fmaf(bf2f(u6.z), w1.z, x2); x3 = fmaf(bf2f(u6.w), w1.z, x3);
            x0 = fmaf(bf2f(u7.x), w1.w, x0); x1 = fmaf(bf2f(u7.y), w1.w, x1);
            x2 = fmaf(bf2f(u7.z), w1.w, x2); x3 = fmaf(bf2f(u7.w), w1.w, x3);
        }
        float o0 = fmaxf(x0 + bb.x, 0.f);
        float o1 = fmaxf(x1 + bb.y, 0.f);
        float o2 = fmaxf(x2 + bb.z, 0.f);
        float o3 = fmaxf(x3 + bb.w, 0.f);
        ushort4 ov;
        ov.x = f2bf(o0); ov.y = f2bf(o1); ov.z = f2bf(o2); ov.w = f2bf(o3);
        *(ushort4*)(vout + (long)n * CDIM + c0) = ov;
        a0 += o0; q0 = fmaf(o0, o0, q0);
        a1 += o1; q1 = fmaf(o1, o1, q1);
        a2 += o2; q2 = fmaf(o2, o2, q2);
        a3 += o3; q3 = fmaf(o3, o3, q3);
    }
    atomicAdd(&s_sum[c0+0], a0); atomicAdd(&s_sum[c0+1], a1);
    atomicAdd(&s_sum[c0+2], a2); atomicAdd(&s_sum[c0+3], a3);
    atomicAdd(&s_sq[c0+0], q0);  atomicAdd(&s_sq[c0+1], q1);
    atomicAdd(&s_sq[c0+2], q2);  atomicAdd(&s_sq[c0+3], q3);
    __syncthreads();
    if (t < CDIM) { atomicAdd(&sum[t], s_sum[t]); atomicAdd(&sq[t], s_sq[t]); }
}

// ---------------- final: out = bn0(x) + bn2(v2), v2 bf16 ----------------
__global__ __launch_bounds__(256) void final_kernel(const float* __restrict__ x,
                                                    const unsigned short* __restrict__ v,
                                                    const float* __restrict__ sc0,
                                                    const float* __restrict__ bi0,
                                                    const float* __restrict__ sc2,
                                                    const float* __restrict__ bi2,
                                                    float* __restrict__ out, int N) {
    int t = threadIdx.x;
    int cg = t & 31, rg = t >> 5;
    int c0 = cg * 4;
    float4 s0 = *(const float4*)(sc0 + c0);
    float4 b0 = *(const float4*)(bi0 + c0);
    float4 s2 = *(const float4*)(sc2 + c0);
    float4 b2 = *(const float4*)(bi2 + c0);
    for (long row = (long)blockIdx.x * 8 + rg; row < N; row += (long)gridDim.x * 8) {
        float4 xv = *(const float4*)(x + row * CDIM + c0);
        ushort4 vv = *(const ushort4*)(v + row * CDIM + c0);
        float4 o;
        o.x = fmaf(xv.x, s0.x, b0.x) + fmaf(bf2f(vv.x), s2.x, b2.x);
        o.y = fmaf(xv.y, s0.y, b0.y) + fmaf(bf2f(vv.y), s2.y, b2.y);
        o.z = fmaf(xv.z, s0.z, b0.z) + fmaf(bf2f(vv.z), s2.z, b2.z);
        o.w = fmaf(xv.w, s0.w, b0.w) + fmaf(bf2f(vv.w), s2.w, b2.w);
        *(float4*)(out + row * CDIM + c0) = o;
    }
}

static inline size_t align16(size_t x) { return (x + 15) & ~(size_t)15; }

extern "C" void kernel_launch(void* const* d_in, const int* in_sizes, int n_in,
                              void* d_out, int out_size, void* d_ws, size_t ws_size,
                              hipStream_t stream) {
    const float* x   = (const float*)d_in[0];
    const int*   ei  = (const int*)d_in[1];
    const float* g0  = (const float*)d_in[2];
    const float* be0 = (const float*)d_in[3];
    const float* W1  = (const float*)d_in[4];
    const float* b1  = (const float*)d_in[5];
    const float* g1  = (const float*)d_in[6];
    const float* be1 = (const float*)d_in[7];
    const float* W2  = (const float*)d_in[8];
    const float* b2  = (const float*)d_in[9];
    const float* g2  = (const float*)d_in[10];
    const float* be2 = (const float*)d_in[11];
    float* out = (float*)d_out;

    int N = in_sizes[0] / CDIM;
    int E = in_sizes[1] / 2;
    const int* src = ei;
    const int* dst = ei + E;

    size_t NC = (size_t)N * CDIM;
    size_t CAP = (size_t)E + 8 * (size_t)N;  // padded CSR capacity

    char* p = (char*)d_ws;
    unsigned short* Bb = (unsigned short*)p;  p += align16(NC * 2);
    unsigned short* Cb = (unsigned short*)p;  p += align16(NC * 2);
    float* dinv  = (float*)p;                 p += align16((size_t)N * 4);
    float* stat  = (float*)p;                 p += align16(768 * 4);
    int*   deg   = (int*)p;                   p += align16((size_t)N * 4);
    int*   rowst = (int*)p;                   p += align16(((size_t)N + 8) * 4);
    int*   cursor= (int*)p;                   p += align16((size_t)N * 4);
    int*   csr   = (int*)p;                   p += align16(CAP * 4);
    float* wcsr  = (float*)p;                 p += align16(CAP * 4);
    int*   part  = (int*)p;                   p += align16(256 * 4);
    float* sb    = (float*)p;                 p += align16(768 * 4);
    unsigned short* wt1 = (unsigned short*)p; p += align16((size_t)CDIM * CDIM * 2);
    unsigned short* wt2 = (unsigned short*)p;

    float* sum0 = stat;       float* sq0 = stat + 128;
    float* sum1 = stat + 256; float* sq1 = stat + 384;
    float* sum2 = stat + 512; float* sq2 = stat + 640;
    float* sc0 = sb;          float* bi0 = sb + 128;
    float* sc1 = sb + 256;    float* bi1 = sb + 384;
    float* sc2 = sb + 512;    float* bi2 = sb + 640;

    float inv_n = 1.0f / (float)N;
    int P = (N + 1023) / 1024;

    // zero stats (768 f) + deg (N ints): contiguous region
    hipMemsetAsync(stat, 0, align16(768 * 4) + (size_t)N * 4, stream);
    // zero padded csr + wcsr (pads: src=0, w=0.0f)
    hipMemsetAsync(csr, 0, align16(CAP * 4) + CAP * 4, stream);

    // ---- CSR build (padded-to-8 segments, shared by both layers) ----
    hist_kernel<<<(E + 255) / 256, 256, 0, stream>>>(dst, deg, E);
    scan1_kernel<<<P, 256, 0, stream>>>(deg, part, N);
    scan2_kernel<<<1, 256, 0, stream>>>(part, P);
    scan3_kernel<<<P, 256, 0, stream>>>(deg, part, rowst, cursor, dinv, N);
    scatter_kernel<<<(E + 255) / 256, 256, 0, stream>>>(src, dst, cursor, dinv, csr, wcsr, E);

    // ---- weight prep (bf16, transposed) ----
    wprep_kernel<<<16, 256, 0, stream>>>(W1, wt1);
    wprep_kernel<<<16, 256, 0, stream>>>(W2, wt2);

    // ---- bn0 stats ----
    stats_kernel<<<1024, 256, 0, stream>>>(x, N, sum0, sq0);
    prep_kernel<<<1, 128, 0, stream>>>(sum0, sq0, g0, be0, sc0, bi0, inv_n);

    // ---- layer 1 ----
    gemm_mfma_kernel<false><<<(N + 127) / 128, 256, 0, stream>>>(x, wt1, sc0, bi0, Bb, N);
    gather_kernel<<<2048, 256, 0, stream>>>(Bb, rowst, csr, wcsr, dinv, b1, Cb, N, sum1, sq1);
    prep_kernel<<<1, 128, 0, stream>>>(sum1, sq1, g1, be1, sc1, bi1, inv_n);

    // ---- layer 2 ----
    gemm_mfma_kernel<true><<<(N + 127) / 128, 256, 0, stream>>>(Cb, wt2, sc1, bi1, Bb, N);
    gather_kernel<<<2048, 256, 0, stream>>>(Bb, rowst, csr, wcsr, dinv, b2, Cb, N, sum2, sq2);
    prep_kernel<<<1, 128, 0, stream>>>(sum2, sq2, g2, be2, sc2, bi2, inv_n);

    // ---- out = bn0(x) + bn2(v2) ----
    final_kernel<<<1024, 256, 0, stream>>>(x, Cb, sc0, bi0, sc2, bi2, out, N);
}

// Round 6
// 437.259 us; speedup vs baseline: 1.0523x; 1.0523x over previous
//
#include <hip/hip_runtime.h>

#define CDIM 128
#define KPAD 136
#define EPS 1e-5f

typedef __attribute__((ext_vector_type(8))) short short8;
typedef __attribute__((ext_vector_type(4))) float f32x4;

__device__ __forceinline__ float bf2f(unsigned short u) {
    union { unsigned int i; float f; } v; v.i = ((unsigned int)u) << 16; return v.f;
}
__device__ __forceinline__ unsigned short f2bf(float f) {
    union { float f; unsigned int i; } v; v.f = f;
    unsigned int u = v.i;
    return (unsigned short)((u + 0x7FFFu + ((u >> 16) & 1u)) >> 16);  // RNE
}

// ---------------- int degree histogram ----------------
__global__ __launch_bounds__(256) void hist_kernel(const int* __restrict__ dst,
                                                   int* __restrict__ deg, int E) {
    int e = blockIdx.x * 256 + threadIdx.x;
    if (e < E) atomicAdd(&deg[dst[e]], 1);
}

// ---------------- scan stage 1: per-1024-chunk sums of degrees padded to 16 ----------
__global__ __launch_bounds__(256) void scan1_kernel(const int* __restrict__ deg,
                                                    int* __restrict__ part, int N) {
    int t = threadIdx.x;
    int base = blockIdx.x * 1024 + t * 4;
    int s = 0;
    if (base + 3 < N) {
        int4 v = *(const int4*)(deg + base);
        s = ((v.x + 15) & ~15) + ((v.y + 15) & ~15) + ((v.z + 15) & ~15) + ((v.w + 15) & ~15);
    } else {
        for (int k = 0; k < 4; ++k) { int i = base + k; if (i < N) s += (deg[i] + 15) & ~15; }
    }
    for (int off = 32; off; off >>= 1) s += __shfl_down(s, off, 64);
    __shared__ int sh[4];
    if ((t & 63) == 0) sh[t >> 6] = s;
    __syncthreads();
    if (t == 0) part[blockIdx.x] = sh[0] + sh[1] + sh[2] + sh[3];
}

// ---------------- scan stage 2: exclusive scan of <=256 partials ----------------
__global__ __launch_bounds__(256) void scan2_kernel(int* __restrict__ part, int P) {
    int t = threadIdx.x;
    __shared__ int sh[256];
    int v = (t < P) ? part[t] : 0;
    sh[t] = v;
    __syncthreads();
    for (int off = 1; off < 256; off <<= 1) {
        int u = (t >= off) ? sh[t - off] : 0;
        __syncthreads();
        sh[t] += u;
        __syncthreads();
    }
    if (t < P) part[t] = sh[t] - v;  // exclusive
}

// ---------------- scan stage 3: padded rowstart + cursor + dinv ----------------
__global__ __launch_bounds__(256) void scan3_kernel(const int* __restrict__ deg,
                                                    const int* __restrict__ part,
                                                    int* __restrict__ rowst,
                                                    int* __restrict__ cursor,
                                                    float* __restrict__ dinv, int N) {
    int t = threadIdx.x, b = blockIdx.x;
    int base = b * 1024 + t * 4;
    int d0 = 0, d1 = 0, d2 = 0, d3 = 0;
    if (base + 3 < N) {
        int4 v = *(const int4*)(deg + base);
        d0 = v.x; d1 = v.y; d2 = v.z; d3 = v.w;
    } else {
        if (base < N)     d0 = deg[base];
        if (base + 1 < N) d1 = deg[base + 1];
        if (base + 2 < N) d2 = deg[base + 2];
        if (base + 3 < N) d3 = deg[base + 3];
    }
    int p0 = (d0 + 15) & ~15, p1 = (d1 + 15) & ~15, p2 = (d2 + 15) & ~15, p3 = (d3 + 15) & ~15;
    int c0 = p0, c1 = c0 + p1, c2 = c1 + p2, c3 = c2 + p3;
    __shared__ int sh[256];
    sh[t] = c3;
    __syncthreads();
    for (int off = 1; off < 256; off <<= 1) {
        int u = (t >= off) ? sh[t - off] : 0;
        __syncthreads();
        sh[t] += u;
        __syncthreads();
    }
    int basev = part[b] + sh[t] - c3;
    int r0 = basev, r1 = basev + c0, r2 = basev + c1, r3 = basev + c2;
    if (base < N)     { rowst[base] = r0;     cursor[base] = r0;     dinv[base]   = rsqrtf((float)d0 + 1.0f); if (base == N - 1)     rowst[N] = r0 + p0; }
    if (base + 1 < N) { rowst[base + 1] = r1; cursor[base + 1] = r1; dinv[base+1] = rsqrtf((float)d1 + 1.0f); if (base + 1 == N - 1) rowst[N] = r1 + p1; }
    if (base + 2 < N) { rowst[base + 2] = r2; cursor[base + 2] = r2; dinv[base+2] = rsqrtf((float)d2 + 1.0f); if (base + 2 == N - 1) rowst[N] = r2 + p2; }
    if (base + 3 < N) { rowst[base + 3] = r3; cursor[base + 3] = r3; dinv[base+3] = rsqrtf((float)d3 + 1.0f); if (base + 3 == N - 1) rowst[N] = r3 + p3; }
}

// ------- scatter (src, weight) pairs into padded interleaved CSR -------
__global__ __launch_bounds__(256) void scatter_kernel(const int* __restrict__ src,
                                                      const int* __restrict__ dst,
                                                      int* __restrict__ cursor,
                                                      const float* __restrict__ dinv,
                                                      int2* __restrict__ ew, int E) {
    int e = blockIdx.x * 256 + threadIdx.x;
    if (e < E) {
        int d = dst[e];
        int s = src[e];
        int pos = atomicAdd(&cursor[d], 1);
        ew[pos] = make_int2(s, __float_as_int(dinv[s] * dinv[d]));
    }
}

// ------- fused misc: blocks 0-15 wprep W1, 16-31 wprep W2, 32+ bn0 stats on x -------
__global__ __launch_bounds__(256) void misc_kernel(const float* __restrict__ W1,
                                                   const float* __restrict__ W2,
                                                   unsigned short* __restrict__ wt1,
                                                   unsigned short* __restrict__ wt2,
                                                   const float* __restrict__ x, int N,
                                                   float* __restrict__ sum,
                                                   float* __restrict__ sq) {
    int b = blockIdx.x;
    if (b < 32) {
        const float* W = (b < 16) ? W1 : W2;
        unsigned short* Wt = (b < 16) ? wt1 : wt2;
        int t = (b & 15) * 256 + threadIdx.x;  // 4096 threads over 16 blocks
        int k = t >> 5, n0 = (t & 31) * 4;
        float4 w = *(const float4*)(W + k * CDIM + n0);
        Wt[(n0 + 0) * CDIM + k] = f2bf(w.x);
        Wt[(n0 + 1) * CDIM + k] = f2bf(w.y);
        Wt[(n0 + 2) * CDIM + k] = f2bf(w.z);
        Wt[(n0 + 3) * CDIM + k] = f2bf(w.w);
        return;
    }
    // ---- stats over x ----
    __shared__ float s_sum[CDIM];
    __shared__ float s_sq[CDIM];
    int t = threadIdx.x;
    if (t < CDIM) { s_sum[t] = 0.f; s_sq[t] = 0.f; }
    __syncthreads();
    int cg = t & 31, rg = t >> 5;
    int c0 = cg * 4;
    int sb = b - 32, sg = (int)gridDim.x - 32;
    float a0=0,a1=0,a2=0,a3=0,q0=0,q1=0,q2=0,q3=0;
    for (long row = (long)sb * 8 + rg; row < N; row += (long)sg * 8) {
        float4 x4 = *(const float4*)(x + row * CDIM + c0);
        a0 += x4.x; q0 = fmaf(x4.x, x4.x, q0);
        a1 += x4.y; q1 = fmaf(x4.y, x4.y, q1);
        a2 += x4.z; q2 = fmaf(x4.z, x4.z, q2);
        a3 += x4.w; q3 = fmaf(x4.w, x4.w, q3);
    }
    atomicAdd(&s_sum[c0+0], a0); atomicAdd(&s_sum[c0+1], a1);
    atomicAdd(&s_sum[c0+2], a2); atomicAdd(&s_sum[c0+3], a3);
    atomicAdd(&s_sq[c0+0], q0);  atomicAdd(&s_sq[c0+1], q1);
    atomicAdd(&s_sq[c0+2], q2);  atomicAdd(&s_sq[c0+3], q3);
    __syncthreads();
    if (t < CDIM) { atomicAdd(&sum[t], s_sum[t]); atomicAdd(&sq[t], s_sq[t]); }
}

// ---------------- MFMA GEMM (64-row tiles, LDS-staged W, folded BN-prep) ----------
// Y = bf16( (scale*X+bias) @ W ); scale/bias computed in-block from sums.
// A/B fragments use the SAME assumed k-slot mapping (invariant to HW bijection);
// C/D layout per m89: col=lane&15, row=(lane>>4)*4+reg.
template<bool BF16_IN>
__global__ __launch_bounds__(256) void gemm_mfma_kernel(const void* __restrict__ Xv,
                                                        const unsigned short* __restrict__ Wt,
                                                        const float* __restrict__ sum,
                                                        const float* __restrict__ sq,
                                                        const float* __restrict__ gamma,
                                                        const float* __restrict__ beta,
                                                        float inv_n,
                                                        unsigned short* __restrict__ Y, int N) {
    __shared__ unsigned short As[64 * KPAD];
    __shared__ unsigned short Ws[CDIM * KPAD];
    __shared__ float scs[CDIM];
    __shared__ float bis[CDIM];
    int t = threadIdx.x;
    if (t < CDIM) {
        float m = sum[t] * inv_n;
        float var = fmaf(-m, m, sq[t] * inv_n);
        float r = rsqrtf(var + EPS);
        float g = gamma[t] * r;
        scs[t] = g;
        bis[t] = fmaf(-m, g, beta[t]);
    }
    __syncthreads();

    long row0 = (long)blockIdx.x * 64;
    // stage Wt -> Ws (16384 ushorts)
    #pragma unroll
    for (int p = 0; p < 16; ++p) {
        int idx = p * 256 + t;
        int n = idx >> 5, c4 = (idx & 31) * 4;
        ushort4 w = *(const ushort4*)(Wt + n * CDIM + c4);
        *(ushort4*)&Ws[n * KPAD + c4] = w;
    }
    // stage A rows: BN-apply + bf16 cvt
    #pragma unroll
    for (int p = 0; p < 8; ++p) {
        int idx = p * 256 + t;
        int r = idx >> 5, c4 = (idx & 31) * 4;
        long row = row0 + r;
        float4 v;
        if (row < N) {
            if (BF16_IN) {
                ushort4 u = *(const ushort4*)((const unsigned short*)Xv + row * CDIM + c4);
                v = make_float4(bf2f(u.x), bf2f(u.y), bf2f(u.z), bf2f(u.w));
            } else {
                v = *(const float4*)((const float*)Xv + row * CDIM + c4);
            }
        } else {
            v = make_float4(0.f, 0.f, 0.f, 0.f);
        }
        float4 sc = *(const float4*)(scs + c4);
        float4 bi = *(const float4*)(bis + c4);
        ushort4 o;
        o.x = f2bf(fmaf(v.x, sc.x, bi.x));
        o.y = f2bf(fmaf(v.y, sc.y, bi.y));
        o.z = f2bf(fmaf(v.z, sc.z, bi.z));
        o.w = f2bf(fmaf(v.w, sc.w, bi.w));
        *(ushort4*)&As[r * KPAD + c4] = o;
    }
    __syncthreads();

    int lane = t & 63, wv = t >> 6;
    int m = lane & 15, hi = lane >> 4;
    const unsigned short* arow = &As[(wv * 16 + m) * KPAD + hi * 8];
    short8 a0 = *(const short8*)(arow);
    short8 a1 = *(const short8*)(arow + 32);
    short8 a2 = *(const short8*)(arow + 64);
    short8 a3 = *(const short8*)(arow + 96);
    f32x4 acc[8];
    #pragma unroll
    for (int nt = 0; nt < 8; ++nt) {
        const unsigned short* brow = &Ws[(nt * 16 + m) * KPAD + hi * 8];
        short8 b0 = *(const short8*)(brow);
        short8 b1 = *(const short8*)(brow + 32);
        short8 b2 = *(const short8*)(brow + 64);
        short8 b3 = *(const short8*)(brow + 96);
        f32x4 c = {0.f, 0.f, 0.f, 0.f};
        c = __builtin_amdgcn_mfma_f32_16x16x32_bf16(a0, b0, c, 0, 0, 0);
        c = __builtin_amdgcn_mfma_f32_16x16x32_bf16(a1, b1, c, 0, 0, 0);
        c = __builtin_amdgcn_mfma_f32_16x16x32_bf16(a2, b2, c, 0, 0, 0);
        c = __builtin_amdgcn_mfma_f32_16x16x32_bf16(a3, b3, c, 0, 0, 0);
        acc[nt] = c;
    }
    __syncthreads();
    // repack C to LDS (reuse As) for coalesced stores
    #pragma unroll
    for (int nt = 0; nt < 8; ++nt) {
        #pragma unroll
        for (int rg = 0; rg < 4; ++rg) {
            int rr = wv * 16 + hi * 4 + rg;
            As[rr * KPAD + nt * 16 + m] = f2bf(acc[nt][rg]);
        }
    }
    __syncthreads();
    #pragma unroll
    for (int p = 0; p < 8; ++p) {
        int idx = p * 256 + t;
        int r = idx >> 5, c4 = (idx & 31) * 4;
        long row = row0 + r;
        if (row < N) {
            ushort4 o = *(const ushort4*)&As[r * KPAD + c4];
            *(ushort4*)(Y + row * CDIM + c4) = o;
        }
    }
}

// ------ fused gather-agg + self-loop + bias + relu + BN stats (16-wide padded CSR) ------
__global__ __launch_bounds__(256) void gather_kernel(const unsigned short* __restrict__ h,
                                                     const int* __restrict__ rowst,
                                                     const int2* __restrict__ ew,
                                                     const float* __restrict__ dinv,
                                                     const float* __restrict__ bvec,
                                                     unsigned short* __restrict__ vout, int N,
                                                     float* __restrict__ sum,
                                                     float* __restrict__ sq) {
    __shared__ float s_sum[CDIM];
    __shared__ float s_sq[CDIM];
    int t = threadIdx.x;
    if (t < CDIM) { s_sum[t] = 0.f; s_sq[t] = 0.f; }
    __syncthreads();
    int grp = t >> 5, lane = t & 31;
    int c0 = lane * 4;
    float4 bb = *(const float4*)(bvec + c0);
    float a0=0,a1=0,a2=0,a3=0,q0=0,q1=0,q2=0,q3=0;
    int ngroups = gridDim.x * 8;
    for (int n = blockIdx.x * 8 + grp; n < N; n += ngroups) {
        int j = rowst[n], e = rowst[n + 1];  // padded: (e-j) % 16 == 0
        float dn = dinv[n];
        float d2 = dn * dn;
        ushort4 hn = *(const ushort4*)(h + (long)n * CDIM + c0);
        float x0 = bf2f(hn.x) * d2, x1 = bf2f(hn.y) * d2;
        float x2 = bf2f(hn.z) * d2, x3 = bf2f(hn.w) * d2;
        for (; j < e; j += 16) {
            int4 pp[8];
            #pragma unroll
            for (int k = 0; k < 8; ++k) pp[k] = *(const int4*)(ew + j + 2 * k);
            ushort4 u[16];
            float w[16];
            #pragma unroll
            for (int k = 0; k < 8; ++k) {
                w[2*k]   = __int_as_float(pp[k].y);
                w[2*k+1] = __int_as_float(pp[k].w);
                u[2*k]   = *(const ushort4*)(h + (long)pp[k].x * CDIM + c0);
                u[2*k+1] = *(const ushort4*)(h + (long)pp[k].z * CDIM + c0);
            }
            #pragma unroll
            for (int k = 0; k < 16; ++k) {
                x0 = fmaf(bf2f(u[k].x), w[k], x0);
                x1 = fmaf(bf2f(u[k].y), w[k], x1);
                x2 = fmaf(bf2f(u[k].z), w[k], x2);
                x3 = fmaf(bf2f(u[k].w), w[k], x3);
            }
        }
        float o0 = fmaxf(x0 + bb.x, 0.f);
        float o1 = fmaxf(x1 + bb.y, 0.f);
        float o2 = fmaxf(x2 + bb.z, 0.f);
        float o3 = fmaxf(x3 + bb.w, 0.f);
        ushort4 ov;
        ov.x = f2bf(o0); ov.y = f2bf(o1); ov.z = f2bf(o2); ov.w = f2bf(o3);
        *(ushort4*)(vout + (long)n * CDIM + c0) = ov;
        a0 += o0; q0 = fmaf(o0, o0, q0);
        a1 += o1; q1 = fmaf(o1, o1, q1);
        a2 += o2; q2 = fmaf(o2, o2, q2);
        a3 += o3; q3 = fmaf(o3, o3, q3);
    }
    atomicAdd(&s_sum[c0+0], a0); atomicAdd(&s_sum[c0+1], a1);
    atomicAdd(&s_sum[c0+2], a2); atomicAdd(&s_sum[c0+3], a3);
    atomicAdd(&s_sq[c0+0], q0);  atomicAdd(&s_sq[c0+1], q1);
    atomicAdd(&s_sq[c0+2], q2);  atomicAdd(&s_sq[c0+3], q3);
    __syncthreads();
    if (t < CDIM) { atomicAdd(&sum[t], s_sum[t]); atomicAdd(&sq[t], s_sq[t]); }
}

// ------- final: out = bn0(x) + bn2(v2), both BN-preps folded in -------
__global__ __launch_bounds__(256) void final_kernel(const float* __restrict__ x,
                                                    const unsigned short* __restrict__ v,
                                                    const float* __restrict__ sum0,
                                                    const float* __restrict__ sq0,
                                                    const float* __restrict__ g0,
                                                    const float* __restrict__ be0,
                                                    const float* __restrict__ sum2,
                                                    const float* __restrict__ sq2,
                                                    const float* __restrict__ g2,
                                                    const float* __restrict__ be2,
                                                    float inv_n,
                                                    float* __restrict__ out, int N) {
    __shared__ float l_s0[CDIM], l_b0[CDIM], l_s2[CDIM], l_b2[CDIM];
    int t = threadIdx.x;
    if (t < CDIM) {
        float m = sum0[t] * inv_n;
        float var = fmaf(-m, m, sq0[t] * inv_n);
        float r = rsqrtf(var + EPS);
        float g = g0[t] * r;
        l_s0[t] = g; l_b0[t] = fmaf(-m, g, be0[t]);
        m = sum2[t] * inv_n;
        var = fmaf(-m, m, sq2[t] * inv_n);
        r = rsqrtf(var + EPS);
        g = g2[t] * r;
        l_s2[t] = g; l_b2[t] = fmaf(-m, g, be2[t]);
    }
    __syncthreads();
    int cg = t & 31, rg = t >> 5;
    int c0 = cg * 4;
    float4 s0 = *(const float4*)(l_s0 + c0);
    float4 b0 = *(const float4*)(l_b0 + c0);
    float4 s2 = *(const float4*)(l_s2 + c0);
    float4 b2 = *(const float4*)(l_b2 + c0);
    for (long row = (long)blockIdx.x * 8 + rg; row < N; row += (long)gridDim.x * 8) {
        float4 xv = *(const float4*)(x + row * CDIM + c0);
        ushort4 vv = *(const ushort4*)(v + row * CDIM + c0);
        float4 o;
        o.x = fmaf(xv.x, s0.x, b0.x) + fmaf(bf2f(vv.x), s2.x, b2.x);
        o.y = fmaf(xv.y, s0.y, b0.y) + fmaf(bf2f(vv.y), s2.y, b2.y);
        o.z = fmaf(xv.z, s0.z, b0.z) + fmaf(bf2f(vv.z), s2.z, b2.z);
        o.w = fmaf(xv.w, s0.w, b0.w) + fmaf(bf2f(vv.w), s2.w, b2.w);
        *(float4*)(out + row * CDIM + c0) = o;
    }
}

static inline size_t align16(size_t x) { return (x + 15) & ~(size_t)15; }

extern "C" void kernel_launch(void* const* d_in, const int* in_sizes, int n_in,
                              void* d_out, int out_size, void* d_ws, size_t ws_size,
                              hipStream_t stream) {
    const float* x   = (const float*)d_in[0];
    const int*   ei  = (const int*)d_in[1];
    const float* g0  = (const float*)d_in[2];
    const float* be0 = (const float*)d_in[3];
    const float* W1  = (const float*)d_in[4];
    const float* b1  = (const float*)d_in[5];
    const float* g1  = (const float*)d_in[6];
    const float* be1 = (const float*)d_in[7];
    const float* W2  = (const float*)d_in[8];
    const float* b2  = (const float*)d_in[9];
    const float* g2  = (const float*)d_in[10];
    const float* be2 = (const float*)d_in[11];
    float* out = (float*)d_out;

    int N = in_sizes[0] / CDIM;
    int E = in_sizes[1] / 2;
    const int* src = ei;
    const int* dst = ei + E;

    size_t NC = (size_t)N * CDIM;
    size_t CAP = (size_t)E + 16 * (size_t)N + 16;  // padded-to-16 CSR capacity

    char* p = (char*)d_ws;
    unsigned short* Bb = (unsigned short*)p;  p += align16(NC * 2);
    unsigned short* Cb = (unsigned short*)p;  p += align16(NC * 2);
    float* dinv  = (float*)p;                 p += align16((size_t)N * 4);
    // ---- zeroed contiguous region: stat(768f) + deg(N) + ew(CAP int2) ----
    float* stat  = (float*)p;                 p += align16(768 * 4);
    int*   deg   = (int*)p;                   p += align16((size_t)N * 4);
    int2*  ew    = (int2*)p;                  p += align16(CAP * 8);
    char*  zend  = p;
    // ---- not zeroed ----
    int*   rowst = (int*)p;                   p += align16(((size_t)N + 16) * 4);
    int*   cursor= (int*)p;                   p += align16((size_t)N * 4);
    int*   part  = (int*)p;                   p += align16(256 * 4);
    unsigned short* wt1 = (unsigned short*)p; p += align16((size_t)CDIM * CDIM * 2);
    unsigned short* wt2 = (unsigned short*)p;

    float* sum0 = stat;       float* sq0 = stat + 128;
    float* sum1 = stat + 256; float* sq1 = stat + 384;
    float* sum2 = stat + 512; float* sq2 = stat + 640;

    float inv_n = 1.0f / (float)N;
    int P = (N + 1023) / 1024;

    // one memset for stats + deg + padded ew (pads: src=0, w=0.0f)
    hipMemsetAsync(stat, 0, (size_t)(zend - (char*)stat), stream);

    // ---- CSR build (padded-to-16 segments, shared by both layers) ----
    hist_kernel<<<(E + 255) / 256, 256, 0, stream>>>(dst, deg, E);
    scan1_kernel<<<P, 256, 0, stream>>>(deg, part, N);
    scan2_kernel<<<1, 256, 0, stream>>>(part, P);
    scan3_kernel<<<P, 256, 0, stream>>>(deg, part, rowst, cursor, dinv, N);
    scatter_kernel<<<(E + 255) / 256, 256, 0, stream>>>(src, dst, cursor, dinv, ew, E);

    // ---- weight prep (x2) + bn0 stats, fused ----
    misc_kernel<<<1056, 256, 0, stream>>>(W1, W2, wt1, wt2, x, N, sum0, sq0);

    // ---- layer 1 ----
    gemm_mfma_kernel<false><<<(N + 63) / 64, 256, 0, stream>>>(x, wt1, sum0, sq0, g0, be0, inv_n, Bb, N);
    gather_kernel<<<2048, 256, 0, stream>>>(Bb, rowst, ew, dinv, b1, Cb, N, sum1, sq1);

    // ---- layer 2 ----
    gemm_mfma_kernel<true><<<(N + 63) / 64, 256, 0, stream>>>(Cb, wt2, sum1, sq1, g1, be1, inv_n, Bb, N);
    gather_kernel<<<2048, 256, 0, stream>>>(Bb, rowst, ew, dinv, b2, Cb, N, sum2, sq2);

    // ---- out = bn0(x) + bn2(v2), preps folded ----
    final_kernel<<<1024, 256, 0, stream>>>(x, Cb, sum0, sq0, g0, be0, sum2, sq2, g2, be2, inv_n, out, N);
}

// Round 8
// 426.605 us; speedup vs baseline: 1.0786x; 1.0250x over previous
//
#include <hip/hip_runtime.h>

#define CDIM 128
#define KPAD 136
#define EPS 1e-5f

typedef __attribute__((ext_vector_type(8))) short short8;
typedef __attribute__((ext_vector_type(4))) float f32x4;
typedef __attribute__((ext_vector_type(4))) int i32x4;

__device__ __forceinline__ float bf2f(unsigned short u) {
    union { unsigned int i; float f; } v; v.i = ((unsigned int)u) << 16; return v.f;
}
__device__ __forceinline__ unsigned short f2bf(float f) {
    union { float f; unsigned int i; } v; v.f = f;
    unsigned int u = v.i;
    return (unsigned short)((u + 0x7FFFu + ((u >> 16) & 1u)) >> 16);  // RNE
}

// ---------------- int degree histogram ----------------
__global__ __launch_bounds__(256) void hist_kernel(const int* __restrict__ dst,
                                                   int* __restrict__ deg, int E) {
    int e = blockIdx.x * 256 + threadIdx.x;
    if (e < E) atomicAdd(&deg[dst[e]], 1);
}

// ---------------- scan stage 1: per-1024-chunk sums of degrees padded to 8 ----------
__global__ __launch_bounds__(256) void scan1_kernel(const int* __restrict__ deg,
                                                    int* __restrict__ part, int N) {
    int t = threadIdx.x;
    int base = blockIdx.x * 1024 + t * 4;
    int s = 0;
    if (base + 3 < N) {
        int4 v = *(const int4*)(deg + base);
        s = ((v.x + 7) & ~7) + ((v.y + 7) & ~7) + ((v.z + 7) & ~7) + ((v.w + 7) & ~7);
    } else {
        for (int k = 0; k < 4; ++k) { int i = base + k; if (i < N) s += (deg[i] + 7) & ~7; }
    }
    for (int off = 32; off; off >>= 1) s += __shfl_down(s, off, 64);
    __shared__ int sh[4];
    if ((t & 63) == 0) sh[t >> 6] = s;
    __syncthreads();
    if (t == 0) part[blockIdx.x] = sh[0] + sh[1] + sh[2] + sh[3];
}

// ---------------- scan stage 2: exclusive scan of <=256 partials ----------------
__global__ __launch_bounds__(256) void scan2_kernel(int* __restrict__ part, int P) {
    int t = threadIdx.x;
    __shared__ int sh[256];
    int v = (t < P) ? part[t] : 0;
    sh[t] = v;
    __syncthreads();
    for (int off = 1; off < 256; off <<= 1) {
        int u = (t >= off) ? sh[t - off] : 0;
        __syncthreads();
        sh[t] += u;
        __syncthreads();
    }
    if (t < P) part[t] = sh[t] - v;  // exclusive
}

// ---------------- scan stage 3: padded rowstart + cursor + dinv ----------------
__global__ __launch_bounds__(256) void scan3_kernel(const int* __restrict__ deg,
                                                    const int* __restrict__ part,
                                                    int* __restrict__ rowst,
                                                    int* __restrict__ cursor,
                                                    float* __restrict__ dinv, int N) {
    int t = threadIdx.x, b = blockIdx.x;
    int base = b * 1024 + t * 4;
    int d0 = 0, d1 = 0, d2 = 0, d3 = 0;
    if (base + 3 < N) {
        int4 v = *(const int4*)(deg + base);
        d0 = v.x; d1 = v.y; d2 = v.z; d3 = v.w;
    } else {
        if (base < N)     d0 = deg[base];
        if (base + 1 < N) d1 = deg[base + 1];
        if (base + 2 < N) d2 = deg[base + 2];
        if (base + 3 < N) d3 = deg[base + 3];
    }
    int p0 = (d0 + 7) & ~7, p1 = (d1 + 7) & ~7, p2 = (d2 + 7) & ~7, p3 = (d3 + 7) & ~7;
    int c0 = p0, c1 = c0 + p1, c2 = c1 + p2, c3 = c2 + p3;
    __shared__ int sh[256];
    sh[t] = c3;
    __syncthreads();
    for (int off = 1; off < 256; off <<= 1) {
        int u = (t >= off) ? sh[t - off] : 0;
        __syncthreads();
        sh[t] += u;
        __syncthreads();
    }
    int basev = part[b] + sh[t] - c3;
    int r0 = basev, r1 = basev + c0, r2 = basev + c1, r3 = basev + c2;
    if (base < N)     { rowst[base] = r0;     cursor[base] = r0;     dinv[base]   = rsqrtf((float)d0 + 1.0f); if (base == N - 1)     rowst[N] = r0 + p0; }
    if (base + 1 < N) { rowst[base + 1] = r1; cursor[base + 1] = r1; dinv[base+1] = rsqrtf((float)d1 + 1.0f); if (base + 1 == N - 1) rowst[N] = r1 + p1; }
    if (base + 2 < N) { rowst[base + 2] = r2; cursor[base + 2] = r2; dinv[base+2] = rsqrtf((float)d2 + 1.0f); if (base + 2 == N - 1) rowst[N] = r2 + p2; }
    if (base + 3 < N) { rowst[base + 3] = r3; cursor[base + 3] = r3; dinv[base+3] = rsqrtf((float)d3 + 1.0f); if (base + 3 == N - 1) rowst[N] = r3 + p3; }
}

// ------- scatter (src, weight) pairs into padded interleaved CSR -------
__global__ __launch_bounds__(256) void scatter_kernel(const int* __restrict__ src,
                                                      const int* __restrict__ dst,
                                                      int* __restrict__ cursor,
                                                      const float* __restrict__ dinv,
                                                      int2* __restrict__ ew, int E) {
    int e = blockIdx.x * 256 + threadIdx.x;
    if (e < E) {
        int d = dst[e];
        int s = src[e];
        int pos = atomicAdd(&cursor[d], 1);
        ew[pos] = make_int2(s, __float_as_int(dinv[s] * dinv[d]));
    }
}

// ------- fused misc: blocks 0-15 wprep W1, 16-31 wprep W2, 32+ bn0 stats on x -------
__global__ __launch_bounds__(256) void misc_kernel(const float* __restrict__ W1,
                                                   const float* __restrict__ W2,
                                                   unsigned short* __restrict__ wt1,
                                                   unsigned short* __restrict__ wt2,
                                                   const float* __restrict__ x, int N,
                                                   float* __restrict__ sum,
                                                   float* __restrict__ sq) {
    int b = blockIdx.x;
    if (b < 32) {
        const float* W = (b < 16) ? W1 : W2;
        unsigned short* Wt = (b < 16) ? wt1 : wt2;
        int t = (b & 15) * 256 + threadIdx.x;  // 4096 threads over 16 blocks
        int k = t >> 5, n0 = (t & 31) * 4;
        float4 w = *(const float4*)(W + k * CDIM + n0);
        Wt[(n0 + 0) * CDIM + k] = f2bf(w.x);
        Wt[(n0 + 1) * CDIM + k] = f2bf(w.y);
        Wt[(n0 + 2) * CDIM + k] = f2bf(w.z);
        Wt[(n0 + 3) * CDIM + k] = f2bf(w.w);
        return;
    }
    // ---- stats over x ----
    __shared__ float s_sum[CDIM];
    __shared__ float s_sq[CDIM];
    int t = threadIdx.x;
    if (t < CDIM) { s_sum[t] = 0.f; s_sq[t] = 0.f; }
    __syncthreads();
    int cg = t & 31, rg = t >> 5;
    int c0 = cg * 4;
    int sb = b - 32, sg = (int)gridDim.x - 32;
    float a0=0,a1=0,a2=0,a3=0,q0=0,q1=0,q2=0,q3=0;
    for (long row = (long)sb * 8 + rg; row < N; row += (long)sg * 8) {
        float4 x4 = *(const float4*)(x + row * CDIM + c0);
        a0 += x4.x; q0 = fmaf(x4.x, x4.x, q0);
        a1 += x4.y; q1 = fmaf(x4.y, x4.y, q1);
        a2 += x4.z; q2 = fmaf(x4.z, x4.z, q2);
        a3 += x4.w; q3 = fmaf(x4.w, x4.w, q3);
    }
    atomicAdd(&s_sum[c0+0], a0); atomicAdd(&s_sum[c0+1], a1);
    atomicAdd(&s_sum[c0+2], a2); atomicAdd(&s_sum[c0+3], a3);
    atomicAdd(&s_sq[c0+0], q0);  atomicAdd(&s_sq[c0+1], q1);
    atomicAdd(&s_sq[c0+2], q2);  atomicAdd(&s_sq[c0+3], q3);
    __syncthreads();
    if (t < CDIM) { atomicAdd(&sum[t], s_sum[t]); atomicAdd(&sq[t], s_sq[t]); }
}

// ---------------- MFMA GEMM (64-row tiles, LDS-staged W, folded BN-prep) ----------
template<bool BF16_IN>
__global__ __launch_bounds__(256) void gemm_mfma_kernel(const void* __restrict__ Xv,
                                                        const unsigned short* __restrict__ Wt,
                                                        const float* __restrict__ sum,
                                                        const float* __restrict__ sq,
                                                        const float* __restrict__ gamma,
                                                        const float* __restrict__ beta,
                                                        float inv_n,
                                                        unsigned short* __restrict__ Y, int N) {
    __shared__ unsigned short As[64 * KPAD];
    __shared__ unsigned short Ws[CDIM * KPAD];
    __shared__ float scs[CDIM];
    __shared__ float bis[CDIM];
    int t = threadIdx.x;
    if (t < CDIM) {
        float m = sum[t] * inv_n;
        float var = fmaf(-m, m, sq[t] * inv_n);
        float r = rsqrtf(var + EPS);
        float g = gamma[t] * r;
        scs[t] = g;
        bis[t] = fmaf(-m, g, beta[t]);
    }
    __syncthreads();

    long row0 = (long)blockIdx.x * 64;
    #pragma unroll
    for (int p = 0; p < 16; ++p) {
        int idx = p * 256 + t;
        int n = idx >> 5, c4 = (idx & 31) * 4;
        ushort4 w = *(const ushort4*)(Wt + n * CDIM + c4);
        *(ushort4*)&Ws[n * KPAD + c4] = w;
    }
    #pragma unroll
    for (int p = 0; p < 8; ++p) {
        int idx = p * 256 + t;
        int r = idx >> 5, c4 = (idx & 31) * 4;
        long row = row0 + r;
        float4 v;
        if (row < N) {
            if (BF16_IN) {
                ushort4 u = *(const ushort4*)((const unsigned short*)Xv + row * CDIM + c4);
                v = make_float4(bf2f(u.x), bf2f(u.y), bf2f(u.z), bf2f(u.w));
            } else {
                v = *(const float4*)((const float*)Xv + row * CDIM + c4);
            }
        } else {
            v = make_float4(0.f, 0.f, 0.f, 0.f);
        }
        float4 sc = *(const float4*)(scs + c4);
        float4 bi = *(const float4*)(bis + c4);
        ushort4 o;
        o.x = f2bf(fmaf(v.x, sc.x, bi.x));
        o.y = f2bf(fmaf(v.y, sc.y, bi.y));
        o.z = f2bf(fmaf(v.z, sc.z, bi.z));
        o.w = f2bf(fmaf(v.w, sc.w, bi.w));
        *(ushort4*)&As[r * KPAD + c4] = o;
    }
    __syncthreads();

    int lane = t & 63, wv = t >> 6;
    int m = lane & 15, hi = lane >> 4;
    const unsigned short* arow = &As[(wv * 16 + m) * KPAD + hi * 8];
    short8 a0 = *(const short8*)(arow);
    short8 a1 = *(const short8*)(arow + 32);
    short8 a2 = *(const short8*)(arow + 64);
    short8 a3 = *(const short8*)(arow + 96);
    f32x4 acc[8];
    #pragma unroll
    for (int nt = 0; nt < 8; ++nt) {
        const unsigned short* brow = &Ws[(nt * 16 + m) * KPAD + hi * 8];
        short8 b0 = *(const short8*)(brow);
        short8 b1 = *(const short8*)(brow + 32);
        short8 b2 = *(const short8*)(brow + 64);
        short8 b3 = *(const short8*)(brow + 96);
        f32x4 c = {0.f, 0.f, 0.f, 0.f};
        c = __builtin_amdgcn_mfma_f32_16x16x32_bf16(a0, b0, c, 0, 0, 0);
        c = __builtin_amdgcn_mfma_f32_16x16x32_bf16(a1, b1, c, 0, 0, 0);
        c = __builtin_amdgcn_mfma_f32_16x16x32_bf16(a2, b2, c, 0, 0, 0);
        c = __builtin_amdgcn_mfma_f32_16x16x32_bf16(a3, b3, c, 0, 0, 0);
        acc[nt] = c;
    }
    __syncthreads();
    #pragma unroll
    for (int nt = 0; nt < 8; ++nt) {
        #pragma unroll
        for (int rg = 0; rg < 4; ++rg) {
            int rr = wv * 16 + hi * 4 + rg;
            As[rr * KPAD + nt * 16 + m] = f2bf(acc[nt][rg]);
        }
    }
    __syncthreads();
    #pragma unroll
    for (int p = 0; p < 8; ++p) {
        int idx = p * 256 + t;
        int r = idx >> 5, c4 = (idx & 31) * 4;
        long row = row0 + r;
        if (row < N) {
            ushort4 o = *(const ushort4*)&As[r * KPAD + c4];
            *(ushort4*)(Y + row * CDIM + c4) = o;
        }
    }
}

// ------ fused gather-agg (8-wide padded CSR, next-node prefetch, NT edge loads) ------
__global__ __launch_bounds__(256) void gather_kernel(const unsigned short* __restrict__ h,
                                                     const int* __restrict__ rowst,
                                                     const int2* __restrict__ ew,
                                                     const float* __restrict__ dinv,
                                                     const float* __restrict__ bvec,
                                                     unsigned short* __restrict__ vout, int N,
                                                     float* __restrict__ sum,
                                                     float* __restrict__ sq) {
    __shared__ float s_sum[CDIM];
    __shared__ float s_sq[CDIM];
    int t = threadIdx.x;
    if (t < CDIM) { s_sum[t] = 0.f; s_sq[t] = 0.f; }
    __syncthreads();
    int grp = t >> 5, lane = t & 31;
    int c0 = lane * 4;
    float4 bb = *(const float4*)(bvec + c0);
    float a0=0,a1=0,a2=0,a3=0,q0=0,q1=0,q2=0,q3=0;
    int ngroups = gridDim.x * 8;
    int n = blockIdx.x * 8 + grp;
    int jn = 0, en = 0; float dnn = 0.f;
    if (n < N) { jn = rowst[n]; en = rowst[n + 1]; dnn = dinv[n]; }
    while (n < N) {
        int j = jn, e = en;
        float dn = dnn;
        int n2 = n + ngroups;
        if (n2 < N) { jn = rowst[n2]; en = rowst[n2 + 1]; dnn = dinv[n2]; }  // prefetch next
        float d2 = dn * dn;
        ushort4 hn = *(const ushort4*)(h + (long)n * CDIM + c0);
        float x0 = bf2f(hn.x) * d2, x1 = bf2f(hn.y) * d2;
        float x2 = bf2f(hn.z) * d2, x3 = bf2f(hn.w) * d2;
        for (; j < e; j += 8) {
            i32x4 p0 = __builtin_nontemporal_load((const i32x4*)(ew + j));
            i32x4 p1 = __builtin_nontemporal_load((const i32x4*)(ew + j + 2));
            i32x4 p2 = __builtin_nontemporal_load((const i32x4*)(ew + j + 4));
            i32x4 p3 = __builtin_nontemporal_load((const i32x4*)(ew + j + 6));
            ushort4 u0 = *(const ushort4*)(h + (long)p0.x * CDIM + c0);
            ushort4 u1 = *(const ushort4*)(h + (long)p0.z * CDIM + c0);
            ushort4 u2 = *(const ushort4*)(h + (long)p1.x * CDIM + c0);
            ushort4 u3 = *(const ushort4*)(h + (long)p1.z * CDIM + c0);
            ushort4 u4 = *(const ushort4*)(h + (long)p2.x * CDIM + c0);
            ushort4 u5 = *(const ushort4*)(h + (long)p2.z * CDIM + c0);
            ushort4 u6 = *(const ushort4*)(h + (long)p3.x * CDIM + c0);
            ushort4 u7 = *(const ushort4*)(h + (long)p3.z * CDIM + c0);
            float w0 = __int_as_float(p0.y), w1 = __int_as_float(p0.w);
            float w2 = __int_as_float(p1.y), w3 = __int_as_float(p1.w);
            float w4 = __int_as_float(p2.y), w5 = __int_as_float(p2.w);
            float w6 = __int_as_float(p3.y), w7 = __int_as_float(p3.w);
            x0 = fmaf(bf2f(u0.x), w0, x0); x1 = fmaf(bf2f(u0.y), w0, x1);
            x2 = fmaf(bf2f(u0.z), w0, x2); x3 = fmaf(bf2f(u0.w), w0, x3);
            x0 = fmaf(bf2f(u1.x), w1, x0); x1 = fmaf(bf2f(u1.y), w1, x1);
            x2 = fmaf(bf2f(u1.z), w1, x2); x3 = fmaf(bf2f(u1.w), w1, x3);
            x0 = fmaf(bf2f(u2.x), w2, x0); x1 = fmaf(bf2f(u2.y), w2, x1);
            x2 = fmaf(bf2f(u2.z), w2, x2); x3 = fmaf(bf2f(u2.w), w2, x3);
            x0 = fmaf(bf2f(u3.x), w3, x0); x1 = fmaf(bf2f(u3.y), w3, x1);
            x2 = fmaf(bf2f(u3.z), w3, x2); x3 = fmaf(bf2f(u3.w), w3, x3);
            x0 = fmaf(bf2f(u4.x), w4, x0); x1 = fmaf(bf2f(u4.y), w4, x1);
            x2 = fmaf(bf2f(u4.z), w4, x2); x3 = fmaf(bf2f(u4.w), w4, x3);
            x0 = fmaf(bf2f(u5.x), w5, x0); x1 = fmaf(bf2f(u5.y), w5, x1);
            x2 = fmaf(bf2f(u5.z), w5, x2); x3 = fmaf(bf2f(u5.w), w5, x3);
            x0 = fmaf(bf2f(u6.x), w6, x0); x1 = fmaf(bf2f(u6.y), w6, x1);
            x2 = fmaf(bf2f(u6.z), w6, x2); x3 = fmaf(bf2f(u6.w), w6, x3);
            x0 = fmaf(bf2f(u7.x), w7, x0); x1 = fmaf(bf2f(u7.y), w7, x1);
            x2 = fmaf(bf2f(u7.z), w7, x2); x3 = fmaf(bf2f(u7.w), w7, x3);
        }
        float o0 = fmaxf(x0 + bb.x, 0.f);
        float o1 = fmaxf(x1 + bb.y, 0.f);
        float o2 = fmaxf(x2 + bb.z, 0.f);
        float o3 = fmaxf(x3 + bb.w, 0.f);
        ushort4 ov;
        ov.x = f2bf(o0); ov.y = f2bf(o1); ov.z = f2bf(o2); ov.w = f2bf(o3);
        *(ushort4*)(vout + (long)n * CDIM + c0) = ov;
        a0 += o0; q0 = fmaf(o0, o0, q0);
        a1 += o1; q1 = fmaf(o1, o1, q1);
        a2 += o2; q2 = fmaf(o2, o2, q2);
        a3 += o3; q3 = fmaf(o3, o3, q3);
        n = n2;
    }
    atomicAdd(&s_sum[c0+0], a0); atomicAdd(&s_sum[c0+1], a1);
    atomicAdd(&s_sum[c0+2], a2); atomicAdd(&s_sum[c0+3], a3);
    atomicAdd(&s_sq[c0+0], q0);  atomicAdd(&s_sq[c0+1], q1);
    atomicAdd(&s_sq[c0+2], q2);  atomicAdd(&s_sq[c0+3], q3);
    __syncthreads();
    if (t < CDIM) { atomicAdd(&sum[t], s_sum[t]); atomicAdd(&sq[t], s_sq[t]); }
}

// ------- final: out = bn0(x) + bn2(v2), both BN-preps folded in -------
__global__ __launch_bounds__(256) void final_kernel(const float* __restrict__ x,
                                                    const unsigned short* __restrict__ v,
                                                    const float* __restrict__ sum0,
                                                    const float* __restrict__ sq0,
                                                    const float* __restrict__ g0,
                                                    const float* __restrict__ be0,
                                                    const float* __restrict__ sum2,
                                                    const float* __restrict__ sq2,
                                                    const float* __restrict__ g2,
                                                    const float* __restrict__ be2,
                                                    float inv_n,
                                                    float* __restrict__ out, int N) {
    __shared__ float l_s0[CDIM], l_b0[CDIM], l_s2[CDIM], l_b2[CDIM];
    int t = threadIdx.x;
    if (t < CDIM) {
        float m = sum0[t] * inv_n;
        float var = fmaf(-m, m, sq0[t] * inv_n);
        float r = rsqrtf(var + EPS);
        float g = g0[t] * r;
        l_s0[t] = g; l_b0[t] = fmaf(-m, g, be0[t]);
        m = sum2[t] * inv_n;
        var = fmaf(-m, m, sq2[t] * inv_n);
        r = rsqrtf(var + EPS);
        g = g2[t] * r;
        l_s2[t] = g; l_b2[t] = fmaf(-m, g, be2[t]);
    }
    __syncthreads();
    int cg = t & 31, rg = t >> 5;
    int c0 = cg * 4;
    float4 s0 = *(const float4*)(l_s0 + c0);
    float4 b0 = *(const float4*)(l_b0 + c0);
    float4 s2 = *(const float4*)(l_s2 + c0);
    float4 b2 = *(const float4*)(l_b2 + c0);
    for (long row = (long)blockIdx.x * 8 + rg; row < N; row += (long)gridDim.x * 8) {
        float4 xv = *(const float4*)(x + row * CDIM + c0);
        ushort4 vv = *(const ushort4*)(v + row * CDIM + c0);
        float4 o;
        o.x = fmaf(xv.x, s0.x, b0.x) + fmaf(bf2f(vv.x), s2.x, b2.x);
        o.y = fmaf(xv.y, s0.y, b0.y) + fmaf(bf2f(vv.y), s2.y, b2.y);
        o.z = fmaf(xv.z, s0.z, b0.z) + fmaf(bf2f(vv.z), s2.z, b2.z);
        o.w = fmaf(xv.w, s0.w, b0.w) + fmaf(bf2f(vv.w), s2.w, b2.w);
        *(float4*)(out + row * CDIM + c0) = o;
    }
}

static inline size_t align16(size_t x) { return (x + 15) & ~(size_t)15; }

extern "C" void kernel_launch(void* const* d_in, const int* in_sizes, int n_in,
                              void* d_out, int out_size, void* d_ws, size_t ws_size,
                              hipStream_t stream) {
    const float* x   = (const float*)d_in[0];
    const int*   ei  = (const int*)d_in[1];
    const float* g0  = (const float*)d_in[2];
    const float* be0 = (const float*)d_in[3];
    const float* W1  = (const float*)d_in[4];
    const float* b1  = (const float*)d_in[5];
    const float* g1  = (const float*)d_in[6];
    const float* be1 = (const float*)d_in[7];
    const float* W2  = (const float*)d_in[8];
    const float* b2  = (const float*)d_in[9];
    const float* g2  = (const float*)d_in[10];
    const float* be2 = (const float*)d_in[11];
    float* out = (float*)d_out;

    int N = in_sizes[0] / CDIM;
    int E = in_sizes[1] / 2;
    const int* src = ei;
    const int* dst = ei + E;

    size_t NC = (size_t)N * CDIM;
    size_t CAP = (size_t)E + 8 * (size_t)N + 8;  // padded-to-8 CSR capacity

    char* p = (char*)d_ws;
    unsigned short* Bb = (unsigned short*)p;  p += align16(NC * 2);
    unsigned short* Cb = (unsigned short*)p;  p += align16(NC * 2);
    float* dinv  = (float*)p;                 p += align16((size_t)N * 4);
    // ---- zeroed contiguous region: stat(768f) + deg(N) + ew(CAP int2) ----
    float* stat  = (float*)p;                 p += align16(768 * 4);
    int*   deg   = (int*)p;                   p += align16((size_t)N * 4);
    int2*  ew    = (int2*)p;                  p += align16(CAP * 8);
    char*  zend  = p;
    // ---- not zeroed ----
    int*   rowst = (int*)p;                   p += align16(((size_t)N + 16) * 4);
    int*   cursor= (int*)p;                   p += align16((size_t)N * 4);
    int*   part  = (int*)p;                   p += align16(256 * 4);
    unsigned short* wt1 = (unsigned short*)p; p += align16((size_t)CDIM * CDIM * 2);
    unsigned short* wt2 = (unsigned short*)p;

    float* sum0 = stat;       float* sq0 = stat + 128;
    float* sum1 = stat + 256; float* sq1 = stat + 384;
    float* sum2 = stat + 512; float* sq2 = stat + 640;

    float inv_n = 1.0f / (float)N;
    int P = (N + 1023) / 1024;

    // one memset for stats + deg + padded ew (pads: src=0, w=0.0f)
    hipMemsetAsync(stat, 0, (size_t)(zend - (char*)stat), stream);

    // ---- CSR build (padded-to-8 segments, shared by both layers) ----
    hist_kernel<<<(E + 255) / 256, 256, 0, stream>>>(dst, deg, E);
    scan1_kernel<<<P, 256, 0, stream>>>(deg, part, N);
    scan2_kernel<<<1, 256, 0, stream>>>(part, P);
    scan3_kernel<<<P, 256, 0, stream>>>(deg, part, rowst, cursor, dinv, N);
    scatter_kernel<<<(E + 255) / 256, 256, 0, stream>>>(src, dst, cursor, dinv, ew, E);

    // ---- weight prep (x2) + bn0 stats, fused ----
    misc_kernel<<<1056, 256, 0, stream>>>(W1, W2, wt1, wt2, x, N, sum0, sq0);

    // ---- layer 1 ----
    gemm_mfma_kernel<false><<<(N + 63) / 64, 256, 0, stream>>>(x, wt1, sum0, sq0, g0, be0, inv_n, Bb, N);
    gather_kernel<<<2048, 256, 0, stream>>>(Bb, rowst, ew, dinv, b1, Cb, N, sum1, sq1);

    // ---- layer 2 ----
    gemm_mfma_kernel<true><<<(N + 63) / 64, 256, 0, stream>>>(Cb, wt2, sum1, sq1, g1, be1, inv_n, Bb, N);
    gather_kernel<<<2048, 256, 0, stream>>>(Bb, rowst, ew, dinv, b2, Cb, N, sum2, sq2);

    // ---- out = bn0(x) + bn2(v2), preps folded ----
    final_kernel<<<2048, 256, 0, stream>>>(x, Cb, sum0, sq0, g0, be0, sum2, sq2, g2, be2, inv_n, out, N);
}